// Round 1
// baseline (882.144 us; speedup 1.0000x reference)
//
#include <hip/hip_runtime.h>
#include <hip/hip_bf16.h>

#define NTOK 8192
#define DMODEL 1024
#define NEXP 32

typedef __attribute__((ext_vector_type(8))) short bf16x8;
typedef __attribute__((ext_vector_type(4))) float f32x4;

__device__ __forceinline__ unsigned int pk_bf16(float a, float b) {
  __hip_bfloat162 h = __float22bfloat162_rn(make_float2(a, b));
  union { __hip_bfloat162 h2; unsigned int u; } cv;
  cv.h2 = h;
  return cv.u;
}

// ---------------- gating: split-K partial logits ----------------
// grid = 256 blocks: part = bx>>5 (8 K-parts of 128 d), tb = bx&31 (256 tokens)
__global__ __launch_bounds__(256) void gate_partial(
    const float* __restrict__ x, const float* __restrict__ wg,
    float* __restrict__ partial) {
  __shared__ float Xs[256 * 20];
  int tid = threadIdx.x;
  int part = blockIdx.x >> 5;
  int tb = blockIdx.x & 31;
  int d0 = part * 128;
  float acc[32];
#pragma unroll
  for (int e = 0; e < 32; e++) acc[e] = 0.f;
  for (int ck = 0; ck < 8; ck++) {
    __syncthreads();
#pragma unroll
    for (int q = 0; q < 4; q++) {
      int li = q * 256 + tid;
      int row = li >> 2, j = li & 3;
      float4 v = *reinterpret_cast<const float4*>(
          x + (size_t)(tb * 256 + row) * DMODEL + d0 + ck * 16 + j * 4);
      *reinterpret_cast<float4*>(&Xs[row * 20 + j * 4]) = v;
    }
    __syncthreads();
#pragma unroll
    for (int d4 = 0; d4 < 4; d4++) {
      float4 xv = *reinterpret_cast<const float4*>(&Xs[tid * 20 + d4 * 4]);
      float xs[4] = {xv.x, xv.y, xv.z, xv.w};
#pragma unroll
      for (int dd = 0; dd < 4; dd++) {
        int d = d0 + ck * 16 + d4 * 4 + dd;
        // wg index is wave-uniform -> compiler emits scalar loads
#pragma unroll
        for (int e = 0; e < 32; e++) acc[e] += xs[dd] * wg[d * 32 + e];
      }
    }
  }
  float* dst = partial + ((size_t)part * NTOK + tb * 256 + tid) * 32;
#pragma unroll
  for (int e = 0; e < 32; e += 4)
    *reinterpret_cast<float4*>(dst + e) =
        make_float4(acc[e], acc[e + 1], acc[e + 2], acc[e + 3]);
}

// ---------------- top-2 (stable, lax.top_k tie-break) ----------------
__global__ __launch_bounds__(256) void gate_top2(
    const float* __restrict__ partial, const float* __restrict__ bg,
    float* __restrict__ idx_out, int* __restrict__ eid,
    int* __restrict__ counts) {
  int t = blockIdx.x * 256 + threadIdx.x;
  float l[32];
#pragma unroll
  for (int e = 0; e < 32; e++) l[e] = bg[e];
  for (int p = 0; p < 8; p++) {
    const float* src = partial + ((size_t)p * NTOK + t) * 32;
#pragma unroll
    for (int e = 0; e < 32; e += 4) {
      float4 v = *reinterpret_cast<const float4*>(src + e);
      l[e] += v.x; l[e + 1] += v.y; l[e + 2] += v.z; l[e + 3] += v.w;
    }
  }
  int i0 = 0; float v0 = l[0];
#pragma unroll
  for (int e = 1; e < 32; e++)
    if (l[e] > v0) { v0 = l[e]; i0 = e; }
  int i1 = -1; float v1 = -3.0e38f;
#pragma unroll
  for (int e = 0; e < 32; e++)
    if (e != i0 && l[e] > v1) { v1 = l[e]; i1 = e; }
  // indices chunk of d_out is read as float32 by the harness
  *reinterpret_cast<float2*>(idx_out + t * 2) = make_float2((float)i0, (float)i1);
  eid[t * 2] = i0;
  eid[t * 2 + 1] = i1;
  atomicAdd(&counts[i0], 1);
  atomicAdd(&counts[i1], 1);
}

// ---------------- exclusive scan over 32 expert counts ----------------
__global__ void scan_k(const int* __restrict__ counts, int* __restrict__ offsets) {
  if (threadIdx.x == 0) {
    int s = 0;
    for (int e = 0; e < 32; e++) { offsets[e] = s; s += counts[e]; }
    offsets[32] = s;
  }
}

// ---------------- stable compaction: dispatch order = stable argsort by expert
// block e scans all 16384 slots in order; ballot-prefix gives stable rank.
__global__ __launch_bounds__(256) void build_stable(
    const int* __restrict__ eid, const int* __restrict__ offsets,
    int* __restrict__ tok_list) {
  int e = blockIdx.x;
  int tid = threadIdx.x;
  int lane = tid & 63, wv = tid >> 6;
  __shared__ int wcnt[4];
  int base = offsets[e];
  for (int c = 0; c < 64; c++) {
    int s = c * 256 + tid;
    bool f = (eid[s] == e);
    unsigned long long m = __ballot(f);
    if (lane == 0) wcnt[wv] = __popcll(m);
    __syncthreads();
    int woff = 0;
#pragma unroll
    for (int i = 0; i < 4; i++) woff += (i < wv) ? wcnt[i] : 0;
    int tot = wcnt[0] + wcnt[1] + wcnt[2] + wcnt[3];
    if (f) {
      int rank = woff + __popcll(m & ((1ull << lane) - 1ull));
      tok_list[base + rank] = s >> 1;  // token of this slot
    }
    base += tot;
    __syncthreads();
  }
}

// ---------------- ragged GEMM, 128x128 tile, bf16 MFMA 16x16x32, BK=64 ----
// PHASE 0: H = gelu(X_gather @ W1e + b1e)   (bf16 out to ws)
// PHASE 1: out[(seg+row)>>1] += H_seg @ W2e + b2e   (atomic pair-reduce)
template <int PHASE>
__global__ __launch_bounds__(256) void moe_gemm(
    const float* __restrict__ Wbase, const float* __restrict__ bias,
    const float* __restrict__ X, const __hip_bfloat16* __restrict__ Hin,
    __hip_bfloat16* __restrict__ Hout, float* __restrict__ out,
    const int* __restrict__ tok_list, const int* __restrict__ offsets,
    const int* __restrict__ counts) {
  int e = blockIdx.x >> 3;
  int mt = blockIdx.x & 7;     // cap 1024 rows/expert (mean 512, sd ~22: safe)
  int n_e = counts[e];
  int m0 = mt * 128;
  if (m0 >= n_e) return;
  int n0 = blockIdx.y * 128;
  int seg = offsets[e];
  const float* W = Wbase + (size_t)e * DMODEL * DMODEL;

  __shared__ unsigned short As[128 * 72];  // [m][k] bf16, stride 72 (+8 pad)
  __shared__ unsigned int Bs[128 * 36];    // [n][kpair] bf16x2, stride 36 (+4 pad)

  int tid = threadIdx.x;
  int lane = tid & 63;
  int wid = tid >> 6;
  int wm = (wid >> 1) * 64, wn = (wid & 1) * 64;
  int ml = lane & 15, q = lane >> 4;

  // A-source row per staging task (4 tasks/thread), clamped; epilogue masks
  int asrc[4];
#pragma unroll
  for (int p = 0; p < 4; p++) {
    int li = p * 256 + tid;
    int gr = m0 + (li >> 3);
    int cr = (gr < n_e) ? gr : 0;
    asrc[p] = (PHASE == 0) ? tok_list[seg + cr] : (seg + cr);
  }

  f32x4 acc[4][4];
#pragma unroll
  for (int im = 0; im < 4; im++)
#pragma unroll
    for (int in = 0; in < 4; in++) acc[im][in] = (f32x4){0.f, 0.f, 0.f, 0.f};

  for (int kt = 0; kt < 16; kt++) {
    int k0 = kt * 64;
    __syncthreads();
    // ---- stage A (128 rows x 64 k), cvt fp32->bf16 for PHASE 0 ----
#pragma unroll
    for (int p = 0; p < 4; p++) {
      int li = p * 256 + tid;
      int row = li >> 3, j = li & 7;
      bf16x8 av;
      if (PHASE == 0) {
        const float* s0 = X + (size_t)asrc[p] * DMODEL + k0 + j * 8;
        float4 f0 = *reinterpret_cast<const float4*>(s0);
        float4 f1 = *reinterpret_cast<const float4*>(s0 + 4);
        union { unsigned int u[4]; bf16x8 v; } cv;
        cv.u[0] = pk_bf16(f0.x, f0.y);
        cv.u[1] = pk_bf16(f0.z, f0.w);
        cv.u[2] = pk_bf16(f1.x, f1.y);
        cv.u[3] = pk_bf16(f1.z, f1.w);
        av = cv.v;
      } else {
        av = *reinterpret_cast<const bf16x8*>(
            Hin + (size_t)asrc[p] * DMODEL + k0 + j * 8);
      }
      *reinterpret_cast<bf16x8*>(&As[row * 72 + j * 8]) = av;
    }
    // ---- stage B: K-major fp32 W -> transposed k-pair layout Bs[n][kp] ----
#pragma unroll
    for (int p = 0; p < 4; p++) {
      int li = p * 256 + tid;
      int nn = li & 127, kq = li >> 7;
      const float* src = W + (size_t)(k0 + kq * 8) * DMODEL + n0 + nn;
      float v[8];
#pragma unroll
      for (int i = 0; i < 8; i++) v[i] = src[(size_t)i * DMODEL];  // 256B coalesced/lane-row
      uint4 d;
      d.x = pk_bf16(v[0], v[1]);
      d.y = pk_bf16(v[2], v[3]);
      d.z = pk_bf16(v[4], v[5]);
      d.w = pk_bf16(v[6], v[7]);
      *reinterpret_cast<uint4*>(&Bs[nn * 36 + kq * 4]) = d;
    }
    __syncthreads();
    // ---- compute: 2 k-steps x 16 MFMA ----
#pragma unroll
    for (int s = 0; s < 2; s++) {
      bf16x8 af[4], bfr[4];
#pragma unroll
      for (int im = 0; im < 4; im++)
        af[im] = *reinterpret_cast<const bf16x8*>(
            &As[(wm + im * 16 + ml) * 72 + s * 32 + q * 8]);
#pragma unroll
      for (int in = 0; in < 4; in++)
        bfr[in] = *reinterpret_cast<const bf16x8*>(
            &Bs[(wn + in * 16 + ml) * 36 + s * 16 + q * 4]);
#pragma unroll
      for (int im = 0; im < 4; im++)
#pragma unroll
        for (int in = 0; in < 4; in++)
          acc[im][in] = __builtin_amdgcn_mfma_f32_16x16x32_bf16(
              af[im], bfr[in], acc[im][in], 0, 0, 0);
    }
  }

  // ---- epilogue (C/D layout: col=lane&15, row=quad*4+reg) ----
#pragma unroll
  for (int in = 0; in < 4; in++) {
    int n = n0 + wn + in * 16 + ml;
    float bv = bias[e * DMODEL + n];
#pragma unroll
    for (int im = 0; im < 4; im++) {
#pragma unroll
      for (int r = 0; r < 4; r++) {
        int gr = m0 + wm + im * 16 + q * 4 + r;
        if (gr < n_e) {
          float v = acc[im][in][r] + bv;
          if (PHASE == 0) {
            float g = 0.5f * v * (1.f + erff(v * 0.70710678118654752f));
            Hout[(size_t)(seg + gr) * DMODEL + n] = __float2bfloat16(g);
          } else {
            // reference sums CONSECUTIVE DISPATCH rows: out[dp>>1] += y[dp]
            int dp = seg + gr;
            atomicAdd(out + (size_t)(dp >> 1) * DMODEL + n, v);
          }
        }
      }
    }
  }
}

extern "C" void kernel_launch(void* const* d_in, const int* in_sizes, int n_in,
                              void* d_out, int out_size, void* d_ws,
                              size_t ws_size, hipStream_t stream) {
  const float* x  = (const float*)d_in[0];
  const float* wg = (const float*)d_in[1];
  const float* bg = (const float*)d_in[2];
  const float* w1 = (const float*)d_in[3];
  const float* b1 = (const float*)d_in[4];
  const float* w2 = (const float*)d_in[5];
  const float* b2 = (const float*)d_in[6];
  float* out = (float*)d_out;

  char* w = (char*)d_ws;
  int* counts   = (int*)(w);                 // 32 ints
  int* offsets  = (int*)(w + 256);           // 33 ints
  int* eid      = (int*)(w + 512);           // 16384 ints
  int* tok_list = (int*)(w + 512 + 4 * 16384);
  float* partial = (float*)(w + 512 + 8 * 16384);               // 8x8192x32 f32
  __hip_bfloat16* Hbuf =
      (__hip_bfloat16*)(w + 512 + 8 * 16384 + 4ull * 8 * NTOK * 32);  // 16384x1024 bf16

  hipMemsetAsync(d_ws, 0, 512, stream);  // counts (+ slack)
  hipMemsetAsync(d_out, 0, (size_t)NTOK * DMODEL * sizeof(float), stream);

  gate_partial<<<dim3(256), 256, 0, stream>>>(x, wg, partial);
  gate_top2<<<dim3(32), 256, 0, stream>>>(partial, bg, out + (size_t)NTOK * DMODEL,
                                          eid, counts);
  scan_k<<<1, 64, 0, stream>>>(counts, offsets);
  build_stable<<<dim3(32), 256, 0, stream>>>(eid, offsets, tok_list);
  moe_gemm<0><<<dim3(256, 8), 256, 0, stream>>>(w1, b1, x, nullptr, Hbuf, nullptr,
                                                tok_list, offsets, counts);
  moe_gemm<1><<<dim3(256, 8), 256, 0, stream>>>(w2, b2, nullptr, Hbuf, nullptr, out,
                                                tok_list, offsets, counts);
}

// Round 2
// 865.672 us; speedup vs baseline: 1.0190x; 1.0190x over previous
//
#include <hip/hip_runtime.h>
#include <hip/hip_bf16.h>
#include <math.h>

#define NTOK 8192
#define DMODEL 1024
#define NEXP 32

typedef __attribute__((ext_vector_type(8))) short bf16x8;
typedef __attribute__((ext_vector_type(4))) float f32x4;

__device__ __forceinline__ unsigned int pk_bf16(float a, float b) {
  __hip_bfloat162 h = __float22bfloat162_rn(make_float2(a, b));
  union { __hip_bfloat162 h2; unsigned int u; } cv;
  cv.h2 = h;
  return cv.u;
}

// async global->LDS, 16B per lane, LDS dest = wave-uniform base + lane*16
__device__ __forceinline__ void gl_lds16(const unsigned short* g, unsigned short* l) {
  __builtin_amdgcn_global_load_lds(
      (const __attribute__((address_space(1))) unsigned int*)g,
      (__attribute__((address_space(3))) unsigned int*)l, 16, 0, 0);
}

// ---------------- x fp32 -> bf16 (straight) ----------------
__global__ __launch_bounds__(256) void convert_x(const float* __restrict__ x,
                                                 unsigned short* __restrict__ xb) {
  size_t i = (size_t)(blockIdx.x * 256 + threadIdx.x) * 8;
  float4 f0 = *reinterpret_cast<const float4*>(x + i);
  float4 f1 = *reinterpret_cast<const float4*>(x + i + 4);
  uint4 d;
  d.x = pk_bf16(f0.x, f0.y);
  d.y = pk_bf16(f0.z, f0.w);
  d.z = pk_bf16(f1.x, f1.y);
  d.w = pk_bf16(f1.z, f1.w);
  *reinterpret_cast<uint4*>(xb + i) = d;
}

// ---------------- W [E][K][N] fp32 -> Wt [E][N][K] bf16, 64x64 LDS tiles ----
__global__ __launch_bounds__(256) void transpose_cvt(const float* __restrict__ w,
                                                     unsigned short* __restrict__ wt) {
  int bid = blockIdx.x;
  int e = bid >> 8;
  int tn = (bid >> 4) & 15;
  int tk = bid & 15;
  const float* src = w + ((size_t)e << 20) + ((size_t)(tk * 64) << 10) + tn * 64;
  unsigned short* dst = wt + ((size_t)e << 20) + ((size_t)(tn * 64) << 10) + tk * 64;
  __shared__ unsigned short Ts[64 * 72];
  int t = threadIdx.x;
#pragma unroll
  for (int i = 0; i < 4; i++) {
    int row = i * 16 + (t >> 4);  // k in tile
    int c4 = (t & 15) * 4;        // n in tile
    float4 v = *reinterpret_cast<const float4*>(src + (size_t)row * 1024 + c4);
    uint2 d;
    d.x = pk_bf16(v.x, v.y);
    d.y = pk_bf16(v.z, v.w);
    *reinterpret_cast<uint2*>(&Ts[row * 72 + c4]) = d;
  }
  __syncthreads();
#pragma unroll
  for (int i = 0; i < 2; i++) {
    int n = i * 32 + (t >> 3);  // n in tile
    int c = t & 7;              // 16B chunk of k
    unsigned int u[4];
#pragma unroll
    for (int h = 0; h < 4; h++) {
      unsigned int lo = Ts[(c * 8 + 2 * h) * 72 + n];
      unsigned int hi = Ts[(c * 8 + 2 * h + 1) * 72 + n];
      u[h] = lo | (hi << 16);
    }
    uint4 d = {u[0], u[1], u[2], u[3]};
    *reinterpret_cast<uint4*>(dst + (size_t)n * 1024 + c * 8) = d;
  }
}

// ---------------- gating: split-K partial logits ----------------
__global__ __launch_bounds__(256) void gate_partial(
    const float* __restrict__ x, const float* __restrict__ wg,
    float* __restrict__ partial) {
  __shared__ float Xs[256 * 20];
  int tid = threadIdx.x;
  int part = blockIdx.x >> 5;
  int tb = blockIdx.x & 31;
  int d0 = part * 128;
  float acc[32];
#pragma unroll
  for (int e = 0; e < 32; e++) acc[e] = 0.f;
  for (int ck = 0; ck < 8; ck++) {
    __syncthreads();
#pragma unroll
    for (int q = 0; q < 4; q++) {
      int li = q * 256 + tid;
      int row = li >> 2, j = li & 3;
      float4 v = *reinterpret_cast<const float4*>(
          x + (size_t)(tb * 256 + row) * DMODEL + d0 + ck * 16 + j * 4);
      *reinterpret_cast<float4*>(&Xs[row * 20 + j * 4]) = v;
    }
    __syncthreads();
#pragma unroll
    for (int d4 = 0; d4 < 4; d4++) {
      float4 xv = *reinterpret_cast<const float4*>(&Xs[tid * 20 + d4 * 4]);
      float xs[4] = {xv.x, xv.y, xv.z, xv.w};
#pragma unroll
      for (int dd = 0; dd < 4; dd++) {
        int d = d0 + ck * 16 + d4 * 4 + dd;
#pragma unroll
        for (int e = 0; e < 32; e++) acc[e] += xs[dd] * wg[d * 32 + e];
      }
    }
  }
  float* dst = partial + ((size_t)part * NTOK + tb * 256 + tid) * 32;
#pragma unroll
  for (int e = 0; e < 32; e += 4)
    *reinterpret_cast<float4*>(dst + e) =
        make_float4(acc[e], acc[e + 1], acc[e + 2], acc[e + 3]);
}

// ---------------- top-2 (lax.top_k tie-break) ----------------
__global__ __launch_bounds__(256) void gate_top2(
    const float* __restrict__ partial, const float* __restrict__ bg,
    float* __restrict__ idx_out, int* __restrict__ eid,
    int* __restrict__ counts) {
  int t = blockIdx.x * 256 + threadIdx.x;
  float l[32];
#pragma unroll
  for (int e = 0; e < 32; e++) l[e] = bg[e];
  for (int p = 0; p < 8; p++) {
    const float* src = partial + ((size_t)p * NTOK + t) * 32;
#pragma unroll
    for (int e = 0; e < 32; e += 4) {
      float4 v = *reinterpret_cast<const float4*>(src + e);
      l[e] += v.x; l[e + 1] += v.y; l[e + 2] += v.z; l[e + 3] += v.w;
    }
  }
  int i0 = 0; float v0 = l[0];
#pragma unroll
  for (int e = 1; e < 32; e++)
    if (l[e] > v0) { v0 = l[e]; i0 = e; }
  int i1 = -1; float v1 = -3.0e38f;
#pragma unroll
  for (int e = 0; e < 32; e++)
    if (e != i0 && l[e] > v1) { v1 = l[e]; i1 = e; }
  *reinterpret_cast<float2*>(idx_out + t * 2) = make_float2((float)i0, (float)i1);
  eid[t * 2] = i0;
  eid[t * 2 + 1] = i1;
  atomicAdd(&counts[i0], 1);
  atomicAdd(&counts[i1], 1);
}

// ---------------- exclusive scan over 32 expert counts ----------------
__global__ void scan_k(const int* __restrict__ counts, int* __restrict__ offsets) {
  if (threadIdx.x == 0) {
    int s = 0;
    for (int e = 0; e < 32; e++) { offsets[e] = s; s += counts[e]; }
    offsets[32] = s;
  }
}

// ---------------- stable compaction ----------------
__global__ __launch_bounds__(256) void build_stable(
    const int* __restrict__ eid, const int* __restrict__ offsets,
    int* __restrict__ tok_list) {
  int e = blockIdx.x;
  int tid = threadIdx.x;
  int lane = tid & 63, wv = tid >> 6;
  __shared__ int wcnt[4];
  int base = offsets[e];
  for (int c = 0; c < 64; c++) {
    int s = c * 256 + tid;
    bool f = (eid[s] == e);
    unsigned long long m = __ballot(f);
    if (lane == 0) wcnt[wv] = __popcll(m);
    __syncthreads();
    int woff = 0;
#pragma unroll
    for (int i = 0; i < 4; i++) woff += (i < wv) ? wcnt[i] : 0;
    int tot = wcnt[0] + wcnt[1] + wcnt[2] + wcnt[3];
    if (f) {
      int rank = woff + __popcll(m & ((1ull << lane) - 1ull));
      tok_list[base + rank] = s >> 1;
    }
    base += tot;
    __syncthreads();
  }
}

// ---------------- ragged GEMM: 128x128 tile, BK=64, global_load_lds 16B,
// XOR chunk swizzle (conflict-free b128 frag reads) ----------------
template <int PHASE>
__global__ __launch_bounds__(256) void moe_gemm2(
    const unsigned short* __restrict__ Wt,   // [E][N][K] bf16
    const float* __restrict__ bias,          // [E][1024] fp32
    const unsigned short* __restrict__ Ain,  // bf16 rows of 1024
    unsigned short* __restrict__ Hout, float* __restrict__ out,
    const int* __restrict__ tok_list, const int* __restrict__ offsets,
    const int* __restrict__ counts) {
  int e = blockIdx.x >> 3;
  int mt = blockIdx.x & 7;
  int n_e = counts[e];
  int m0 = mt * 128;
  if (m0 >= n_e) return;
  int n0 = blockIdx.y * 128;
  int seg = offsets[e];

  __shared__ unsigned short As[128 * 64];  // [m][k], unpadded (global_load_lds)
  __shared__ unsigned short Bs[128 * 64];  // [n][k]

  int tid = threadIdx.x, lane = tid & 63, wid = tid >> 6;
  int wm = (wid >> 1) * 64, wn = (wid & 1) * 64;
  int ml = lane & 15, q = lane >> 4;

  // per-lane global element offsets for the 4 staging instrs per operand.
  // chunk j is XOR-swizzled by row so LDS phys chunk = logical ^ (row&7).
  size_t a_off[4], b_off[4];
#pragma unroll
  for (int p = 0; p < 4; p++) {
    int ia = wid * 4 + p;
    int row = ia * 8 + (lane >> 3);       // 0..127 within tile
    int j = (lane & 7) ^ (row & 7);
    int gr = m0 + row;
    int cr = (gr < n_e) ? gr : (n_e - 1);
    int src = (PHASE == 0) ? tok_list[seg + cr] : (seg + cr);
    a_off[p] = (size_t)src * DMODEL + j * 8;
    b_off[p] = ((size_t)e * DMODEL + n0 + row) * DMODEL + j * 8;
  }

  f32x4 acc[4][4];
#pragma unroll
  for (int im = 0; im < 4; im++)
#pragma unroll
    for (int in = 0; in < 4; in++) acc[im][in] = (f32x4){0.f, 0.f, 0.f, 0.f};

  for (int kt = 0; kt < 16; kt++) {
    int k0 = kt * 64;
    __syncthreads();
#pragma unroll
    for (int p = 0; p < 4; p++)
      gl_lds16(Ain + a_off[p] + k0, &As[(wid * 4 + p) * 512]);
#pragma unroll
    for (int p = 0; p < 4; p++)
      gl_lds16(Wt + b_off[p] + k0, &Bs[(wid * 4 + p) * 512]);
    __syncthreads();
#pragma unroll
    for (int s = 0; s < 2; s++) {
      bf16x8 af[4], bfr[4];
#pragma unroll
      for (int im = 0; im < 4; im++) {
        int row = wm + im * 16 + ml;
        int c = (s * 4 + q) ^ (row & 7);
        af[im] = *reinterpret_cast<const bf16x8*>(&As[row * 64 + c * 8]);
      }
#pragma unroll
      for (int in = 0; in < 4; in++) {
        int row = wn + in * 16 + ml;
        int c = (s * 4 + q) ^ (row & 7);
        bfr[in] = *reinterpret_cast<const bf16x8*>(&Bs[row * 64 + c * 8]);
      }
#pragma unroll
      for (int im = 0; im < 4; im++)
#pragma unroll
        for (int in = 0; in < 4; in++)
          acc[im][in] = __builtin_amdgcn_mfma_f32_16x16x32_bf16(
              af[im], bfr[in], acc[im][in], 0, 0, 0);
    }
  }

  // epilogue (C/D: col=lane&15, row=quad*4+reg)
#pragma unroll
  for (int in = 0; in < 4; in++) {
    int n = n0 + wn + in * 16 + ml;
    float bv = bias[e * DMODEL + n];
#pragma unroll
    for (int im = 0; im < 4; im++) {
#pragma unroll
      for (int r = 0; r < 4; r++) {
        int gr = m0 + wm + im * 16 + q * 4 + r;
        if (gr < n_e) {
          float v = acc[im][in][r] + bv;
          if (PHASE == 0) {
            float g = 0.5f * v * (1.f + erff(v * 0.70710678118654752f));
            Hout[(size_t)(seg + gr) * DMODEL + n] = (unsigned short)(
                __hip_bfloat16_raw(__float2bfloat16(g)).x);
          } else {
            int dp = seg + gr;
            atomicAdd(out + (size_t)(dp >> 1) * DMODEL + n, v);
          }
        }
      }
    }
  }
}

extern "C" void kernel_launch(void* const* d_in, const int* in_sizes, int n_in,
                              void* d_out, int out_size, void* d_ws,
                              size_t ws_size, hipStream_t stream) {
  const float* x  = (const float*)d_in[0];
  const float* wg = (const float*)d_in[1];
  const float* bg = (const float*)d_in[2];
  const float* w1 = (const float*)d_in[3];
  const float* b1 = (const float*)d_in[4];
  const float* w2 = (const float*)d_in[5];
  const float* b2 = (const float*)d_in[6];
  float* out = (float*)d_out;

  char* w = (char*)d_ws;
  int* counts   = (int*)(w);                    // 128 B
  int* offsets  = (int*)(w + 256);              // 132 B (inside zeroed 512)
  int* eid      = (int*)(w + 512);              // 64 KB
  int* tok_list = (int*)(w + 512 + 65536);      // 64 KB
  float* partial = (float*)(w + 131584);                        // 8 MB
  unsigned short* Hbuf = (unsigned short*)(w + 131584 + 8388608);        // 33.55 MB
  unsigned short* Xb   = (unsigned short*)(w + 131584 + 8388608 + 33554432);  // 16.78 MB
  unsigned short* w1t  = (unsigned short*)(w + 131584 + 8388608 + 33554432 + 16777216);
  unsigned short* w2t  = (unsigned short*)(w + 131584 + 8388608 + 33554432 + 16777216 + 67108864);
  // total ~193.1 MB

  hipMemsetAsync(d_ws, 0, 512, stream);
  hipMemsetAsync(d_out, 0, (size_t)NTOK * DMODEL * sizeof(float), stream);

  convert_x<<<dim3(4096), 256, 0, stream>>>(x, Xb);
  transpose_cvt<<<dim3(8192), 256, 0, stream>>>(w1, w1t);
  transpose_cvt<<<dim3(8192), 256, 0, stream>>>(w2, w2t);

  gate_partial<<<dim3(256), 256, 0, stream>>>(x, wg, partial);
  gate_top2<<<dim3(32), 256, 0, stream>>>(partial, bg, out + (size_t)NTOK * DMODEL,
                                          eid, counts);
  scan_k<<<1, 64, 0, stream>>>(counts, offsets);
  build_stable<<<dim3(32), 256, 0, stream>>>(eid, offsets, tok_list);

  moe_gemm2<0><<<dim3(256, 8), 256, 0, stream>>>(w1t, b1, Xb, Hbuf, nullptr,
                                                 tok_list, offsets, counts);
  moe_gemm2<1><<<dim3(256, 8), 256, 0, stream>>>(w2t, b2, Hbuf, nullptr, out,
                                                 tok_list, offsets, counts);
}

// Round 3
// 635.405 us; speedup vs baseline: 1.3883x; 1.3624x over previous
//
#include <hip/hip_runtime.h>
#include <hip/hip_bf16.h>
#include <math.h>

#define NTOK 8192
#define DMODEL 1024
#define NEXP 32

typedef __attribute__((ext_vector_type(8))) short bf16x8;
typedef __attribute__((ext_vector_type(4))) float f32x4;

__device__ __forceinline__ unsigned int pk_bf16(float a, float b) {
  __hip_bfloat162 h = __float22bfloat162_rn(make_float2(a, b));
  union { __hip_bfloat162 h2; unsigned int u; } cv;
  cv.h2 = h;
  return cv.u;
}

__device__ __forceinline__ void gl_lds16(const unsigned short* g, unsigned short* l) {
  __builtin_amdgcn_global_load_lds(
      (const __attribute__((address_space(1))) unsigned int*)g,
      (__attribute__((address_space(3))) unsigned int*)l, 16, 0, 0);
}

// ---------------- x fp32 -> bf16 ----------------
__global__ __launch_bounds__(256) void convert_x(const float* __restrict__ x,
                                                 unsigned short* __restrict__ xb) {
  size_t i = (size_t)(blockIdx.x * 256 + threadIdx.x) * 8;
  float4 f0 = *reinterpret_cast<const float4*>(x + i);
  float4 f1 = *reinterpret_cast<const float4*>(x + i + 4);
  uint4 d;
  d.x = pk_bf16(f0.x, f0.y);
  d.y = pk_bf16(f0.z, f0.w);
  d.z = pk_bf16(f1.x, f1.y);
  d.w = pk_bf16(f1.z, f1.w);
  *reinterpret_cast<uint4*>(xb + i) = d;
}

// ---------------- W [E][K][N] fp32 -> Wt [E][N][K] bf16 ----------------
// k-pair packing: one uint = bf16(k even)|bf16(k odd)<<16, so both LDS sides
// are 32-bit+ vectorized. XOR column swizzle keeps banks ~2-way (free).
__global__ __launch_bounds__(256) void transpose_cvt2(const float* __restrict__ w,
                                                      unsigned short* __restrict__ wt) {
  int bid = blockIdx.x;
  int e = bid >> 8;
  int tk = (bid >> 4) & 15;
  int tn = bid & 15;
  const float* src = w + ((size_t)e << 20) + ((size_t)(tk * 64) << 10) + tn * 64;
  unsigned short* dst = wt + ((size_t)e << 20) + ((size_t)(tn * 64) << 10) + tk * 64;
  __shared__ unsigned int Ts[64 * 32];
  int t = threadIdx.x;
  {
    int kp = t >> 3;  // 0..31 (pair of k rows)
    int c8 = t & 7;   // col group of 8
    const float* s0 = src + (size_t)(2 * kp) * 1024 + c8 * 8;
    float4 a0 = *reinterpret_cast<const float4*>(s0);
    float4 a1 = *reinterpret_cast<const float4*>(s0 + 4);
    float4 b0 = *reinterpret_cast<const float4*>(s0 + 1024);
    float4 b1 = *reinterpret_cast<const float4*>(s0 + 1028);
    float av[8] = {a0.x, a0.y, a0.z, a0.w, a1.x, a1.y, a1.z, a1.w};
    float bv[8] = {b0.x, b0.y, b0.z, b0.w, b1.x, b1.y, b1.z, b1.w};
#pragma unroll
    for (int i = 0; i < 8; i++) {
      int n = c8 * 8 + i;
      Ts[n * 32 + (kp ^ (n & 28))] = pk_bf16(av[i], bv[i]);
    }
  }
  __syncthreads();
  {
    int n = t >> 2;
    int kq = t & 3;
#pragma unroll
    for (int h = 0; h < 2; h++) {
      int k4 = kq + h * 4;
      int phys4 = (4 * k4) ^ (n & 28);
      uint4 d = *reinterpret_cast<const uint4*>(&Ts[n * 32 + phys4]);
      *reinterpret_cast<uint4*>(dst + (size_t)n * 1024 + k4 * 8) = d;
    }
  }
}

// ---------------- gating ----------------
__global__ __launch_bounds__(256) void gate_partial(
    const float* __restrict__ x, const float* __restrict__ wg,
    float* __restrict__ partial) {
  __shared__ float Xs[256 * 20];
  int tid = threadIdx.x;
  int part = blockIdx.x >> 5;
  int tb = blockIdx.x & 31;
  int d0 = part * 128;
  float acc[32];
#pragma unroll
  for (int e = 0; e < 32; e++) acc[e] = 0.f;
  for (int ck = 0; ck < 8; ck++) {
    __syncthreads();
#pragma unroll
    for (int q = 0; q < 4; q++) {
      int li = q * 256 + tid;
      int row = li >> 2, j = li & 3;
      float4 v = *reinterpret_cast<const float4*>(
          x + (size_t)(tb * 256 + row) * DMODEL + d0 + ck * 16 + j * 4);
      *reinterpret_cast<float4*>(&Xs[row * 20 + j * 4]) = v;
    }
    __syncthreads();
#pragma unroll
    for (int d4 = 0; d4 < 4; d4++) {
      float4 xv = *reinterpret_cast<const float4*>(&Xs[tid * 20 + d4 * 4]);
      float xs[4] = {xv.x, xv.y, xv.z, xv.w};
#pragma unroll
      for (int dd = 0; dd < 4; dd++) {
        int d = d0 + ck * 16 + d4 * 4 + dd;
#pragma unroll
        for (int e = 0; e < 32; e++) acc[e] += xs[dd] * wg[d * 32 + e];
      }
    }
  }
  float* dst = partial + ((size_t)part * NTOK + tb * 256 + tid) * 32;
#pragma unroll
  for (int e = 0; e < 32; e += 4)
    *reinterpret_cast<float4*>(dst + e) =
        make_float4(acc[e], acc[e + 1], acc[e + 2], acc[e + 3]);
}

__global__ __launch_bounds__(256) void gate_top2(
    const float* __restrict__ partial, const float* __restrict__ bg,
    float* __restrict__ idx_out, int* __restrict__ eid,
    int* __restrict__ counts) {
  int t = blockIdx.x * 256 + threadIdx.x;
  float l[32];
#pragma unroll
  for (int e = 0; e < 32; e++) l[e] = bg[e];
  for (int p = 0; p < 8; p++) {
    const float* src = partial + ((size_t)p * NTOK + t) * 32;
#pragma unroll
    for (int e = 0; e < 32; e += 4) {
      float4 v = *reinterpret_cast<const float4*>(src + e);
      l[e] += v.x; l[e + 1] += v.y; l[e + 2] += v.z; l[e + 3] += v.w;
    }
  }
  int i0 = 0; float v0 = l[0];
#pragma unroll
  for (int e = 1; e < 32; e++)
    if (l[e] > v0) { v0 = l[e]; i0 = e; }
  int i1 = -1; float v1 = -3.0e38f;
#pragma unroll
  for (int e = 0; e < 32; e++)
    if (e != i0 && l[e] > v1) { v1 = l[e]; i1 = e; }
  *reinterpret_cast<float2*>(idx_out + t * 2) = make_float2((float)i0, (float)i1);
  eid[t * 2] = i0;
  eid[t * 2 + 1] = i1;
  atomicAdd(&counts[i0], 1);
  atomicAdd(&counts[i1], 1);
}

__global__ void scan_k(const int* __restrict__ counts, int* __restrict__ offsets) {
  if (threadIdx.x == 0) {
    int s = 0;
    for (int e = 0; e < 32; e++) { offsets[e] = s; s += counts[e]; }
    offsets[32] = s;
  }
}

__global__ __launch_bounds__(256) void build_stable(
    const int* __restrict__ eid, const int* __restrict__ offsets,
    int* __restrict__ tok_list) {
  int e = blockIdx.x;
  int tid = threadIdx.x;
  int lane = tid & 63, wv = tid >> 6;
  __shared__ int wcnt[4];
  int base = offsets[e];
  for (int c = 0; c < 64; c++) {
    int s = c * 256 + tid;
    bool f = (eid[s] == e);
    unsigned long long m = __ballot(f);
    if (lane == 0) wcnt[wv] = __popcll(m);
    __syncthreads();
    int woff = 0;
#pragma unroll
    for (int i = 0; i < 4; i++) woff += (i < wv) ? wcnt[i] : 0;
    int tot = wcnt[0] + wcnt[1] + wcnt[2] + wcnt[3];
    if (f) {
      int rank = woff + __popcll(m & ((1ull << lane) - 1ull));
      tok_list[base + rank] = s >> 1;
    }
    base += tot;
    __syncthreads();
  }
}

// ---------------- ragged GEMM: 128m x 256n tile, 512 thr, BK=32,
// explicit double-buffer with raw s_barrier + manual vmcnt(3) ----------------
template <int PHASE>
__global__ __launch_bounds__(512, 4) void moe_gemm3(
    const unsigned short* __restrict__ Wt, const float* __restrict__ bias,
    const unsigned short* __restrict__ Ain, unsigned short* __restrict__ Hout,
    float* __restrict__ out, const int* __restrict__ tok_list,
    const int* __restrict__ offsets, const int* __restrict__ counts) {
  // bx = nt*512 + mt*64 + e  (e in low bits -> experts spread over XCDs;
  // sibling tiles of one expert keep same bx%8 -> same XCD slot)
  int bx = blockIdx.x;
  int e = bx & 31;
  int mt = (bx >> 5) & 7;
  int nt = bx >> 8;
  int n_e = counts[e];
  int m0 = mt * 128;
  if (m0 >= n_e) return;
  int n0 = nt * 256;
  int seg = offsets[e];

  __shared__ __align__(16) unsigned short As[2][128 * 32];
  __shared__ __align__(16) unsigned short Bs[2][256 * 32];

  int tid = threadIdx.x, lane = tid & 63, wid = tid >> 6;
  int wm = (wid >> 2) * 64, wn = (wid & 3) * 64;
  int ml = lane & 15, q = lane >> 4;

  // per-thread staging sources (1 A-instr, 2 B-instrs per wave per tile)
  int arow = wid * 16 + (lane >> 2);
  int agr = m0 + arow;
  int acr = (agr < n_e) ? agr : (n_e - 1);
  int atok = (PHASE == 0) ? tok_list[seg + acr] : (seg + acr);
  size_t a_off = (size_t)atok * DMODEL + (((lane & 3) ^ (arow & 3)) * 8);
  size_t b_off[2];
#pragma unroll
  for (int p = 0; p < 2; p++) {
    int brow = wid * 32 + p * 16 + (lane >> 2);
    b_off[p] = ((size_t)e * DMODEL + n0 + brow) * DMODEL +
               (((lane & 3) ^ (brow & 3)) * 8);
  }

  f32x4 acc[4][4];
#pragma unroll
  for (int im = 0; im < 4; im++)
#pragma unroll
    for (int in = 0; in < 4; in++) acc[im][in] = (f32x4){0.f, 0.f, 0.f, 0.f};

#define STAGE(BUF, K0)                                                \
  {                                                                   \
    gl_lds16(Ain + a_off + (K0), &As[BUF][wid * 512]);                \
    gl_lds16(Wt + b_off[0] + (K0), &Bs[BUF][(wid * 2) * 512]);        \
    gl_lds16(Wt + b_off[1] + (K0), &Bs[BUF][(wid * 2 + 1) * 512]);    \
  }

  STAGE(0, 0)
  STAGE(1, 32)

  for (int kt = 0; kt < 32; kt++) {
    int buf = kt & 1;
    if (kt < 31)
      asm volatile("s_waitcnt vmcnt(3)" ::: "memory");
    else
      asm volatile("s_waitcnt vmcnt(0)" ::: "memory");
    __builtin_amdgcn_s_barrier();

    bf16x8 af[4], bfr[4];
#pragma unroll
    for (int im = 0; im < 4; im++) {
      int r = wm + im * 16 + ml;
      af[im] = *reinterpret_cast<const bf16x8*>(
          &As[buf][r * 32 + ((q ^ (r & 3)) * 8)]);
    }
#pragma unroll
    for (int in = 0; in < 4; in++) {
      int r = wn + in * 16 + ml;
      bfr[in] = *reinterpret_cast<const bf16x8*>(
          &Bs[buf][r * 32 + ((q ^ (r & 3)) * 8)]);
    }
#pragma unroll
    for (int im = 0; im < 4; im++)
#pragma unroll
      for (int in = 0; in < 4; in++)
        acc[im][in] = __builtin_amdgcn_mfma_f32_16x16x32_bf16(
            af[im], bfr[in], acc[im][in], 0, 0, 0);

    asm volatile("s_waitcnt lgkmcnt(0)" ::: "memory");
    __builtin_amdgcn_s_barrier();
    if (kt < 30) {
      int k0 = (kt + 2) * 32;
      STAGE(buf, k0)
    }
  }
#undef STAGE

  // epilogue (C/D: col=lane&15, row=quad*4+reg)
#pragma unroll
  for (int in = 0; in < 4; in++) {
    int n = n0 + wn + in * 16 + ml;
    float bv = bias[e * DMODEL + n];
#pragma unroll
    for (int im = 0; im < 4; im++) {
      int mb = m0 + wm + im * 16 + q * 4;  // even
      if (PHASE == 0) {
#pragma unroll
        for (int r = 0; r < 4; r++) {
          int gr = mb + r;
          if (gr < n_e) {
            float v = acc[im][in][r] + bv;
            float g = 0.5f * v * (1.f + erff(v * 0.70710678118654752f));
            Hout[(size_t)(seg + gr) * DMODEL + n] =
                (unsigned short)(__hip_bfloat16_raw(__float2bfloat16(g)).x);
          }
        }
      } else {
        float v[4];
        bool ok[4];
#pragma unroll
        for (int r = 0; r < 4; r++) {
          ok[r] = (mb + r) < n_e;
          v[r] = acc[im][in][r] + bv;
        }
        int dp0 = seg + mb;
        if ((seg & 1) == 0) {
          // pairs (r0,r1),(r2,r3) share out row
#pragma unroll
          for (int r = 0; r < 4; r += 2) {
            if (ok[r] && ok[r + 1])
              atomicAdd(out + (size_t)((dp0 + r) >> 1) * DMODEL + n,
                        v[r] + v[r + 1]);
            else {
              if (ok[r]) atomicAdd(out + (size_t)((dp0 + r) >> 1) * DMODEL + n, v[r]);
              if (ok[r + 1])
                atomicAdd(out + (size_t)((dp0 + r + 1) >> 1) * DMODEL + n, v[r + 1]);
            }
          }
        } else {
          if (ok[0]) atomicAdd(out + (size_t)(dp0 >> 1) * DMODEL + n, v[0]);
          if (ok[1] && ok[2])
            atomicAdd(out + (size_t)((dp0 + 1) >> 1) * DMODEL + n, v[1] + v[2]);
          else {
            if (ok[1]) atomicAdd(out + (size_t)((dp0 + 1) >> 1) * DMODEL + n, v[1]);
            if (ok[2]) atomicAdd(out + (size_t)((dp0 + 2) >> 1) * DMODEL + n, v[2]);
          }
          if (ok[3]) atomicAdd(out + (size_t)((dp0 + 3) >> 1) * DMODEL + n, v[3]);
        }
      }
    }
  }
}

extern "C" void kernel_launch(void* const* d_in, const int* in_sizes, int n_in,
                              void* d_out, int out_size, void* d_ws,
                              size_t ws_size, hipStream_t stream) {
  const float* x  = (const float*)d_in[0];
  const float* wg = (const float*)d_in[1];
  const float* bg = (const float*)d_in[2];
  const float* w1 = (const float*)d_in[3];
  const float* b1 = (const float*)d_in[4];
  const float* w2 = (const float*)d_in[5];
  const float* b2 = (const float*)d_in[6];
  float* out = (float*)d_out;

  char* w = (char*)d_ws;
  int* counts   = (int*)(w);
  int* offsets  = (int*)(w + 256);
  int* eid      = (int*)(w + 512);
  int* tok_list = (int*)(w + 512 + 65536);
  float* partial = (float*)(w + 131584);
  unsigned short* Hbuf = (unsigned short*)(w + 131584 + 8388608);
  unsigned short* Xb   = (unsigned short*)(w + 131584 + 8388608 + 33554432);
  unsigned short* w1t  = (unsigned short*)(w + 131584 + 8388608 + 33554432 + 16777216);
  unsigned short* w2t  = (unsigned short*)(w + 131584 + 8388608 + 33554432 + 16777216 + 67108864);

  hipMemsetAsync(d_ws, 0, 512, stream);
  hipMemsetAsync(d_out, 0, (size_t)NTOK * DMODEL * sizeof(float), stream);

  convert_x<<<dim3(4096), 256, 0, stream>>>(x, Xb);
  transpose_cvt2<<<dim3(8192), 256, 0, stream>>>(w1, w1t);
  transpose_cvt2<<<dim3(8192), 256, 0, stream>>>(w2, w2t);

  gate_partial<<<dim3(256), 256, 0, stream>>>(x, wg, partial);
  gate_top2<<<dim3(32), 256, 0, stream>>>(partial, bg, out + (size_t)NTOK * DMODEL,
                                          eid, counts);
  scan_k<<<1, 64, 0, stream>>>(counts, offsets);
  build_stable<<<dim3(32), 256, 0, stream>>>(eid, offsets, tok_list);

  moe_gemm3<0><<<dim3(1024), 512, 0, stream>>>(w1t, b1, Xb, Hbuf, nullptr,
                                               tok_list, offsets, counts);
  moe_gemm3<1><<<dim3(1024), 512, 0, stream>>>(w2t, b2, Hbuf, nullptr, out,
                                               tok_list, offsets, counts);
}